// Round 24
// baseline (125.616 us; speedup 1.0000x reference)
//
#include <hip/hip_runtime.h>
#include <math.h>

typedef _Float16 h16;
typedef __attribute__((ext_vector_type(2))) _Float16 h16x2;
typedef __attribute__((ext_vector_type(4))) _Float16 h16x4;
typedef __attribute__((ext_vector_type(8))) _Float16 h16x8;
typedef __attribute__((ext_vector_type(4))) float f32x4;

#define NBATCH 2048
#define NT 64
#define KK 40
#define NL 7
#define SIGMA 0.02f
#define INVLN2 1.4426950408889634f

// LDS (h16 units). Rotating [40][128] regions RA/RB (P: W^T->G planes, Q: S->W^T_next).
// HCK: H^H [40 k][128 c=2n+ri]. UOF: U [64 n][64 m]. No pad rows anywhere:
// out-of-range rows are handled by register clamp/zero (see phase comments).
#define RA   0
#define RB   (40*128)
#define HCK  (2*40*128)
#define UOF  (3*40*128)
#define LDSH (UOF + 64*64)        // 19456 h16 = 38912 B

#define SWZ(row, c)  ((c) ^ (((row)&7)<<3))
#define SWZW(row, c) ((c) ^ (((row)&15)<<3))
#define MFMA16(a,b,c) __builtin_amdgcn_mfma_f32_16x16x32_f16((a),(b),(c),0,0,0)

static __device__ __forceinline__ float DOT2(h16x2 a, h16x2 b, float c) {
#if __has_builtin(__builtin_amdgcn_fdot2)
    return __builtin_amdgcn_fdot2(a, b, c, false);
#else
    return fmaf((float)a.x, (float)b.x, fmaf((float)a.y, (float)b.y, c));
#endif
}
static __device__ __forceinline__ h16x2 PK(float x, float y) {
    h16x2 r; r.x = (h16)x; r.y = (h16)y; return r;
}
// per 32b word (wr,wi) -> (wi,-wr)
static __device__ __forceinline__ h16x8 conjA(h16x8 v) {
    union { h16x8 h; unsigned u[4]; } x; x.h = v;
    #pragma unroll
    for (int i=0;i<4;++i){ unsigned t=x.u[i]; t=(t>>16)|(t<<16); x.u[i]=t^0x80000000u; }
    return x.h;
}
// per 32b word (sr',-si') -> (si',sr')
static __device__ __forceinline__ h16x8 imB(h16x8 v) {
    union { h16x8 h; unsigned u[4]; } x; x.h = v;
    #pragma unroll
    for (int i=0;i<4;++i){ unsigned t=x.u[i]; t=(t>>16)|(t<<16); x.u[i]=t^0x00008000u; }
    return x.h;
}
// keep fragment if p, else zero
static __device__ __forceinline__ h16x8 zsel(h16x8 v, bool p) {
    union { h16x8 h; unsigned u[4]; } x; x.h = v;
    #pragma unroll
    for (int i=0;i<4;++i) x.u[i] = p ? x.u[i] : 0u;
    return x.h;
}

__global__ __launch_bounds__(256, 2) void gpnet_kernel(
    const float* __restrict__ gHr, const float* __restrict__ gHi,
    const float* __restrict__ gEta, const float* __restrict__ gU,
    const float* __restrict__ gB, float* __restrict__ gOut, int outFloats)
{
    __shared__ __align__(16) h16 sh[LDSH];
    __shared__ float sRed[4];

    const int tid = threadIdx.x;
    const int wv  = tid >> 6;      // wave 0..3
    const int ln  = tid & 63;
    const int col = ln & 15;       // fragment col / row component
    const int g   = ln >> 4;       // k-group

    const int bb = blockIdx.x;
    const float* hr = gHr + (size_t)bb * NT * KK;
    const float* hi = gHi + (size_t)bb * NT * KK;

    // ---- init: H (H^H layout) + W^T = b0 into RA (layer-0 collapse: W1 = b[0])
    for (int i = tid; i < NT*KK; i += 256) {
        int n = i / KK, k = i % KK;
        *(h16x2*)(sh + HCK + k*128 + SWZW(k, 2*n)) = PK(hr[i], hi[i]);
        *(h16x2*)(sh + RA  + k*128 + SWZW(k, 2*n)) = PK(gB[i], 0.f);
    }
    // W-cache (f32 regs) = b0 at owned positions; power
    float Wr[3][4], Wi[3][4];
    float ps = 0.f;
    #pragma unroll
    for (int ct = 0; ct < 3; ++ct)
        #pragma unroll
        for (int r = 0; r < 4; ++r) {
            int n = 16*wv + 4*g + r, l = col + 16*ct;
            float b0 = (l < KK) ? gB[n*KK + l] : 0.f;
            Wr[ct][r] = b0; Wi[ct][r] = 0.f;
            ps += b0 * b0;
        }
    #pragma unroll
    for (int off = 32; off; off >>= 1) ps += __shfl_down(ps, off, 64);
    if (ln == 0) sRed[wv] = ps;
    __syncthreads();

    for (int t = 1; t < NL; ++t) {
        const int P = (t & 1) ? RA : RB;   // W^T at layer start; G planes later
        const int Q = (t & 1) ? RB : RA;   // S/S'; W^T_next after C
        const int GREo = P, GIMo = P + 40*64;

        const float pw   = sRed[0] + sRed[1] + sRed[2] + sRed[3];
        const float cpen = 0.04f * (pw - 1.0f);
        const float etat = gEta[t];

        // early global loads: U[t] pairs and b[t] at owned positions
        float2 ureg[8];
        {
            const float2* u2 = (const float2*)(gU + (size_t)t * NT * NT);
            #pragma unroll
            for (int j = 0; j < 8; ++j) ureg[j] = u2[tid + j*256];
        }
        float breg[3][4];
        #pragma unroll
        for (int ct = 0; ct < 3; ++ct)
            #pragma unroll
            for (int r = 0; r < 4; ++r) {
                int n = 16*wv + 4*g + r, l = col + 16*ct;
                breg[ct][r] = (l < KK) ? gB[(size_t)t*NT*KK + n*KK + l] : 0.f;
            }

        // ---- PHASE A (MFMA, waves 0..2): UNSCALED S^T -> Q. Wave 3: stage U.
        // bf rows kcol>=40: clamp + ZERO (lanes then write S'[l][k>=40] = 0 cols).
        // af rows lrow>=40: clamp only (garbage -> l>=40 outputs, skipped).
        if (wv < 3) {
            f32x4 aRe[3], aIm[3];
            #pragma unroll
            for (int rt = 0; rt < 3; ++rt) { aRe[rt] = (f32x4){0.f,0.f,0.f,0.f}; aIm[rt] = (f32x4){0.f,0.f,0.f,0.f}; }
            const int kcol = col + 16*wv;
            const bool vK = (kcol < KK);
            const int kC = vK ? kcol : 0;
            #pragma unroll
            for (int q = 0; q < 4; ++q) {
                h16x8 bf = *(const h16x8*)(sh + HCK + kC*128 + SWZW(kC, g*8 + 32*q));
                bf = zsel(bf, vK);
                #pragma unroll
                for (int rt = 0; rt < 3; ++rt) {
                    int lrow = col + 16*rt;
                    int lC = (lrow < KK) ? lrow : 0;
                    h16x8 af = *(const h16x8*)(sh + P + lC*128 + SWZW(lC, g*8 + 32*q));
                    aRe[rt] = MFMA16(af, bf, aRe[rt]);        // Re: (wr,wi).(hr,hi)
                    aIm[rt] = MFMA16(conjA(af), bf, aIm[rt]); // Im: (wi,-wr).(hr,hi)
                }
            }
            #pragma unroll
            for (int rt = 0; rt < 3; ++rt)
                #pragma unroll
                for (int r = 0; r < 4; ++r) {
                    int l = 16*rt + 4*g + r;
                    if (l < KK)
                        *(h16x2*)(sh + Q + l*128 + SWZ(l, 2*kcol)) =
                            PK(aRe[rt][r], aIm[rt][r]);
                }
        } else {
            // wave 3: U[t] -> UOF (read by phase C; visible from barrier 1)
            const float2* u2 = (const float2*)(gU + (size_t)t * NT * NT);
            #pragma unroll 8
            for (int j = 0; j < 32; ++j) {
                int e2 = j*64 + ln;
                float2 v = u2[e2];
                int n = e2 >> 5, m2 = (e2 & 31) * 2;
                *(h16x2*)(sh + UOF + n*64 + SWZ(n, m2)) = PK(v.x, v.y);
            }
        }
        __syncthreads();                       // (1) S in Q + U visible

        // ---- coefficients (proven scalar pass): 4 lanes per user k (k<40 only)
        if (tid < 160) {
            const int k = tid >> 2, q = tid & 3;
            h16x2 va[10];
            #pragma unroll
            for (int ii = 0; ii < 10; ++ii)
                va[ii] = *(const h16x2*)(sh + Q + (q*10+ii)*128 + SWZ(q*10+ii, 2*k));
            float rs = 0.f, dd = 0.f;
            #pragma unroll
            for (int ii = 0; ii < 10; ++ii) rs = DOT2(va[ii], va[ii], rs);
            const int dk = k - q*10;
            if (dk >= 0 && dk < 10) dd = DOT2(va[dk], va[dk], 0.f);
            rs += __shfl_xor(rs, 1, 64); rs += __shfl_xor(rs, 2, 64);
            dd += __shfl_xor(dd, 1, 64); dd += __shfl_xor(dd, 2, 64);
            float T  = rs + SIGMA, Is = rs - dd + SIGMA;
            float cA_ = 2.f * INVLN2 / T;
            float cC_ = -2.f * INVLN2 * dd / (Is * T);
            #pragma unroll
            for (int ii = 0; ii < 10; ++ii) {
                int l = q*10 + ii;
                float c = (l == k) ? cA_ : cC_;
                *(h16x2*)(sh + Q + l*128 + SWZ(l, 2*k)) =
                    PK((float)va[ii].x * c, -(float)va[ii].y * c);   // (sr',-si')
            }
        }
        __syncthreads();                       // (2) S' ready; P (old W^T) dead

        // ---- PHASE B (MFMA): G[n][l]; af rebuilt per q from read-only HCK
        // (k>=40 -> 0). bf rows lr>=40: clamp only (garbage -> l>=40, skipped).
        f32x4 gRe[3], gIm[3];
        #pragma unroll
        for (int ct = 0; ct < 3; ++ct) { gRe[ct] = (f32x4){0.f,0.f,0.f,0.f}; gIm[ct] = (f32x4){0.f,0.f,0.f,0.f}; }
        {
            const int nrow = col + 16*wv;
            #pragma unroll
            for (int q = 0; q < 3; ++q) {
                h16x8 af;
                #pragma unroll
                for (int j = 0; j < 8; ++j) af[j] = (h16)0.f;
                if (q < 2 || g < 2) {
                    const int kb = g*4 + 16*q;
                    #pragma unroll
                    for (int i = 0; i < 4; ++i) {
                        h16x2 p = *(const h16x2*)(sh + HCK + (kb+i)*128 + SWZW(kb+i, 2*nrow));
                        af[2*i] = p.x; af[2*i+1] = p.y;
                    }
                }
                #pragma unroll
                for (int ct = 0; ct < 3; ++ct) {
                    int lr = col + 16*ct;
                    int lrC = (lr < KK) ? lr : 0;
                    h16x8 bf = *(const h16x8*)(sh + Q + lrC*128 + SWZ(lrC, g*8 + 32*q));
                    gRe[ct] = MFMA16(af, bf, gRe[ct]);
                    gIm[ct] = MFMA16(af, imB(bf), gIm[ct]);
                }
            }
        }
        // U[t] -> LDS (disjoint region; read by phase C after barrier 4)
        #pragma unroll
        for (int j = 0; j < 8; ++j) {
            int e2 = tid + j*256;
            int n = e2 >> 5, m2 = (e2 & 31) * 2;
            *(h16x2*)(sh + UOF + n*64 + SWZ(n, m2)) = PK(ureg[j].x, ureg[j].y);
        }
        __syncthreads();                       // (3) all Q reads done
        // write G as split planes (packed h16x4); penalty folded into the pack
        {
            const int n0w = 16*wv + 4*g;
            #pragma unroll
            for (int ct = 0; ct < 3; ++ct) {
                int l = col + 16*ct;
                if (l < KK) {
                    h16x4 g4, q4;
                    #pragma unroll
                    for (int r = 0; r < 4; ++r) {
                        g4[r] = (h16)(gRe[ct][r] - cpen * Wr[ct][r]);
                        q4[r] = (h16)(gIm[ct][r] - cpen * Wi[ct][r]);
                    }
                    *(h16x4*)(sh + GREo + l*64 + SWZ(l, n0w)) = g4;
                    *(h16x4*)(sh + GIMo + l*64 + SWZ(l, n0w)) = q4;
                }
            }
        }
        __syncthreads();                       // (4) G planes + U visible

        // ---- PHASE C (MFMA): Ug = U x G. fre/fim rows l>=40: clamp only.
        f32x4 cRe[3], cIm[3];
        #pragma unroll
        for (int ct = 0; ct < 3; ++ct) { cRe[ct] = (f32x4){0.f,0.f,0.f,0.f}; cIm[ct] = (f32x4){0.f,0.f,0.f,0.f}; }
        {
            const int nrow = col + 16*wv;
            #pragma unroll
            for (int q = 0; q < 2; ++q) {
                h16x8 af = *(const h16x8*)(sh + UOF + nrow*64 + SWZ(nrow, g*8 + 32*q));
                #pragma unroll
                for (int ct = 0; ct < 3; ++ct) {
                    const int l = col + 16*ct;
                    const int lC = (l < KK) ? l : 0;
                    h16x8 fre = *(const h16x8*)(sh + GREo + lC*64 + SWZ(lC, g*8 + 32*q));
                    h16x8 fim = *(const h16x8*)(sh + GIMo + lC*64 + SWZ(lC, g*8 + 32*q));
                    cRe[ct] = MFMA16(af, fre, cRe[ct]);
                    cIm[ct] = MFMA16(af, fim, cIm[ct]);
                }
            }
        }
        float ps2 = 0.f;
        {
            const int n0w = 16*wv + 4*g;
            #pragma unroll
            for (int ct = 0; ct < 3; ++ct) {
                int l = col + 16*ct;
                h16x8 wvv;
                #pragma unroll
                for (int r = 0; r < 4; ++r) {
                    float ur = cRe[ct][r], ui = cIm[ct][r];
                    float wr = Wr[ct][r] - etat*(ur - ui) + breg[ct][r];
                    float wi = Wi[ct][r] - etat*(ui + ur);
                    Wr[ct][r] = wr; Wi[ct][r] = wi;
                    wvv[2*r]   = (h16)wr;
                    wvv[2*r+1] = (h16)wi;
                    if (l < KK) ps2 += wr*wr + wi*wi;
                }
                if (t < NL-1 && l < KK)
                    *(h16x8*)(sh + Q + l*128 + SWZW(l, 2*n0w)) = wvv;
            }
        }
        #pragma unroll
        for (int off = 32; off; off >>= 1) ps2 += __shfl_down(ps2, off, 64);
        if (ln == 0) sRed[wv] = ps2;
        __syncthreads();                       // (5) layer end
    }

    // ---- final normalization from registers
    const float pwf   = sRed[0] + sRed[1] + sRed[2] + sRed[3];
    const float scale = 1.0f / (sqrtf(pwf) + 1e-6f);

    if (outFloats >= 2 * NBATCH * NT * KK) {
        float2* ob = (float2*)(gOut + (size_t)bb * NT * KK * 2);
        #pragma unroll
        for (int ct = 0; ct < 3; ++ct)
            #pragma unroll
            for (int r = 0; r < 4; ++r) {
                int n = 16*wv + 4*g + r, l = col + 16*ct;
                if (l < KK) {
                    float2 v; v.x = Wr[ct][r]*scale; v.y = Wi[ct][r]*scale;
                    ob[n*KK + l] = v;
                }
            }
    } else {
        float* ob = gOut + (size_t)bb * NT * KK;
        #pragma unroll
        for (int ct = 0; ct < 3; ++ct)
            #pragma unroll
            for (int r = 0; r < 4; ++r) {
                int n = 16*wv + 4*g + r, l = col + 16*ct;
                if (l < KK) ob[n*KK + l] = Wr[ct][r] * scale;
            }
    }
}

extern "C" void kernel_launch(void* const* d_in, const int* in_sizes, int n_in,
                              void* d_out, int out_size, void* d_ws, size_t ws_size,
                              hipStream_t stream) {
    (void)in_sizes; (void)n_in; (void)d_ws; (void)ws_size;
    const float* Hr  = (const float*)d_in[0];
    const float* Hi  = (const float*)d_in[1];
    const float* eta = (const float*)d_in[2];
    const float* U   = (const float*)d_in[3];
    const float* b   = (const float*)d_in[4];
    float* out = (float*)d_out;
    gpnet_kernel<<<NBATCH, 256, 0, stream>>>(Hr, Hi, eta, U, b, out, out_size);
}

// Round 25
// 112.196 us; speedup vs baseline: 1.1196x; 1.1196x over previous
//
#include <hip/hip_runtime.h>
#include <math.h>

typedef _Float16 h16;
typedef __attribute__((ext_vector_type(2))) _Float16 h16x2;
typedef __attribute__((ext_vector_type(4))) _Float16 h16x4;
typedef __attribute__((ext_vector_type(8))) _Float16 h16x8;
typedef __attribute__((ext_vector_type(4))) float f32x4;

#define NBATCH 2048
#define NT 64
#define KK 40
#define NL 7
#define SIGMA 0.02f
#define INVLN2 1.4426950408889634f

// LDS (h16 units). Rotating [40][128] regions RA/RB (P: W^T->G planes, Q: S->W^T_next).
// HCK: H^H [40 k][128 c=2n+ri]. UOF: U [64 n][64 m]. No pad rows anywhere:
// out-of-range rows are handled by register clamp/zero (see phase comments).
#define RA   0
#define RB   (40*128)
#define HCK  (2*40*128)
#define UOF  (3*40*128)
#define LDSH (UOF + 64*64)        // 19456 h16 = 38912 B

#define SWZ(row, c)  ((c) ^ (((row)&7)<<3))
#define SWZW(row, c) ((c) ^ (((row)&15)<<3))
#define MFMA16(a,b,c) __builtin_amdgcn_mfma_f32_16x16x32_f16((a),(b),(c),0,0,0)

static __device__ __forceinline__ float DOT2(h16x2 a, h16x2 b, float c) {
#if __has_builtin(__builtin_amdgcn_fdot2)
    return __builtin_amdgcn_fdot2(a, b, c, false);
#else
    return fmaf((float)a.x, (float)b.x, fmaf((float)a.y, (float)b.y, c));
#endif
}
static __device__ __forceinline__ h16x2 PK(float x, float y) {
    h16x2 r; r.x = (h16)x; r.y = (h16)y; return r;
}
// per 32b word (wr,wi) -> (wi,-wr)
static __device__ __forceinline__ h16x8 conjA(h16x8 v) {
    union { h16x8 h; unsigned u[4]; } x; x.h = v;
    #pragma unroll
    for (int i=0;i<4;++i){ unsigned t=x.u[i]; t=(t>>16)|(t<<16); x.u[i]=t^0x80000000u; }
    return x.h;
}
// per 32b word (sr',-si') -> (si',sr')
static __device__ __forceinline__ h16x8 imB(h16x8 v) {
    union { h16x8 h; unsigned u[4]; } x; x.h = v;
    #pragma unroll
    for (int i=0;i<4;++i){ unsigned t=x.u[i]; t=(t>>16)|(t<<16); x.u[i]=t^0x00008000u; }
    return x.h;
}
// keep fragment if p, else zero
static __device__ __forceinline__ h16x8 zsel(h16x8 v, bool p) {
    union { h16x8 h; unsigned u[4]; } x; x.h = v;
    #pragma unroll
    for (int i=0;i<4;++i) x.u[i] = p ? x.u[i] : 0u;
    return x.h;
}

__global__ __launch_bounds__(256, 2) void gpnet_kernel(
    const float* __restrict__ gHr, const float* __restrict__ gHi,
    const float* __restrict__ gEta, const float* __restrict__ gU,
    const float* __restrict__ gB, float* __restrict__ gOut, int outFloats)
{
    __shared__ __align__(16) h16 sh[LDSH];
    __shared__ float sRed[4];

    const int tid = threadIdx.x;
    const int wv  = tid >> 6;      // wave 0..3
    const int ln  = tid & 63;
    const int col = ln & 15;       // fragment col / row component
    const int g   = ln >> 4;       // k-group

    const int bb = blockIdx.x;
    const float* hr = gHr + (size_t)bb * NT * KK;
    const float* hi = gHi + (size_t)bb * NT * KK;

    // ---- init: H (H^H layout) + W^T = b0 into RA (layer-0 collapse: W1 = b[0])
    for (int i = tid; i < NT*KK; i += 256) {
        int n = i / KK, k = i % KK;
        *(h16x2*)(sh + HCK + k*128 + SWZW(k, 2*n)) = PK(hr[i], hi[i]);
        *(h16x2*)(sh + RA  + k*128 + SWZW(k, 2*n)) = PK(gB[i], 0.f);
    }
    // W-cache (f32 regs) = b0 at owned positions; power
    float Wr[3][4], Wi[3][4];
    float ps = 0.f;
    #pragma unroll
    for (int ct = 0; ct < 3; ++ct)
        #pragma unroll
        for (int r = 0; r < 4; ++r) {
            int n = 16*wv + 4*g + r, l = col + 16*ct;
            float b0 = (l < KK) ? gB[n*KK + l] : 0.f;
            Wr[ct][r] = b0; Wi[ct][r] = 0.f;
            ps += b0 * b0;
        }
    #pragma unroll
    for (int off = 32; off; off >>= 1) ps += __shfl_down(ps, off, 64);
    if (ln == 0) sRed[wv] = ps;
    __syncthreads();

    // ---- hoisted phase-B A-operand fragments (H, layer-invariant), built from
    // the LDS HCK copy (no extra HBM traffic). paf[q] = H[nrow][g*4+16q ..+3]
    // interleaved (hr,hi); q==2 && g>=2 (k>=40) -> zero (exact K masking).
    h16x8 paf[3];
    {
        const int nrow = col + 16*wv;
        #pragma unroll
        for (int q = 0; q < 3; ++q) {
            h16x8 v;
            #pragma unroll
            for (int j = 0; j < 8; ++j) v[j] = (h16)0.f;
            if (q < 2 || g < 2) {
                const int kb = g*4 + 16*q;
                #pragma unroll
                for (int i = 0; i < 4; ++i) {
                    h16x2 p = *(const h16x2*)(sh + HCK + (kb+i)*128 + SWZW(kb+i, 2*nrow));
                    v[2*i] = p.x; v[2*i+1] = p.y;
                }
            }
            paf[q] = v;
        }
    }

    for (int t = 1; t < NL; ++t) {
        const int P = (t & 1) ? RA : RB;   // W^T at layer start; G planes later
        const int Q = (t & 1) ? RB : RA;   // S/S'; W^T_next after C
        const int GREo = P, GIMo = P + 40*64;

        const float pw   = sRed[0] + sRed[1] + sRed[2] + sRed[3];
        const float cpen = 0.04f * (pw - 1.0f);
        const float etat = gEta[t];

        // b[t] prefetch at owned positions (used in phase C)
        float breg[3][4];
        #pragma unroll
        for (int ct = 0; ct < 3; ++ct)
            #pragma unroll
            for (int r = 0; r < 4; ++r) {
                int n = 16*wv + 4*g + r, l = col + 16*ct;
                breg[ct][r] = (l < KK) ? gB[(size_t)t*NT*KK + n*KK + l] : 0.f;
            }

        // ---- PHASE A (MFMA, waves 0..2): UNSCALED S^T -> Q. Wave 3: stage U.
        // bf rows kcol>=40: clamp + ZERO (lanes then write S'[l][k>=40] = 0 cols).
        // af rows lrow>=40: clamp only (garbage -> l>=40 outputs, skipped).
        if (wv < 3) {
            f32x4 aRe[3], aIm[3];
            #pragma unroll
            for (int rt = 0; rt < 3; ++rt) { aRe[rt] = (f32x4){0.f,0.f,0.f,0.f}; aIm[rt] = (f32x4){0.f,0.f,0.f,0.f}; }
            const int kcol = col + 16*wv;
            const bool vK = (kcol < KK);
            const int kC = vK ? kcol : 0;
            #pragma unroll
            for (int q = 0; q < 4; ++q) {
                h16x8 bf = *(const h16x8*)(sh + HCK + kC*128 + SWZW(kC, g*8 + 32*q));
                bf = zsel(bf, vK);
                #pragma unroll
                for (int rt = 0; rt < 3; ++rt) {
                    int lrow = col + 16*rt;
                    int lC = (lrow < KK) ? lrow : 0;
                    h16x8 af = *(const h16x8*)(sh + P + lC*128 + SWZW(lC, g*8 + 32*q));
                    aRe[rt] = MFMA16(af, bf, aRe[rt]);        // Re: (wr,wi).(hr,hi)
                    aIm[rt] = MFMA16(conjA(af), bf, aIm[rt]); // Im: (wi,-wr).(hr,hi)
                }
            }
            #pragma unroll
            for (int rt = 0; rt < 3; ++rt)
                #pragma unroll
                for (int r = 0; r < 4; ++r) {
                    int l = 16*rt + 4*g + r;
                    if (l < KK)
                        *(h16x2*)(sh + Q + l*128 + SWZ(l, 2*kcol)) =
                            PK(aRe[rt][r], aIm[rt][r]);
                }
        } else {
            // wave 3: U[t] -> UOF (read by phase C; visible from barrier 1)
            const float2* u2 = (const float2*)(gU + (size_t)t * NT * NT);
            #pragma unroll 8
            for (int j = 0; j < 32; ++j) {
                int e2 = j*64 + ln;
                float2 v = u2[e2];
                int n = e2 >> 5, m2 = (e2 & 31) * 2;
                *(h16x2*)(sh + UOF + n*64 + SWZ(n, m2)) = PK(v.x, v.y);
            }
        }
        __syncthreads();                       // (1) S in Q + U visible

        // ---- coefficients (proven scalar pass): 4 lanes per user k (k<40 only)
        if (tid < 160) {
            const int k = tid >> 2, q = tid & 3;
            h16x2 va[10];
            #pragma unroll
            for (int ii = 0; ii < 10; ++ii)
                va[ii] = *(const h16x2*)(sh + Q + (q*10+ii)*128 + SWZ(q*10+ii, 2*k));
            float rs = 0.f, dd = 0.f;
            #pragma unroll
            for (int ii = 0; ii < 10; ++ii) rs = DOT2(va[ii], va[ii], rs);
            const int dk = k - q*10;
            if (dk >= 0 && dk < 10) dd = DOT2(va[dk], va[dk], 0.f);
            rs += __shfl_xor(rs, 1, 64); rs += __shfl_xor(rs, 2, 64);
            dd += __shfl_xor(dd, 1, 64); dd += __shfl_xor(dd, 2, 64);
            float T  = rs + SIGMA, Is = rs - dd + SIGMA;
            float cA_ = 2.f * INVLN2 / T;
            float cC_ = -2.f * INVLN2 * dd / (Is * T);
            #pragma unroll
            for (int ii = 0; ii < 10; ++ii) {
                int l = q*10 + ii;
                float c = (l == k) ? cA_ : cC_;
                *(h16x2*)(sh + Q + l*128 + SWZ(l, 2*k)) =
                    PK((float)va[ii].x * c, -(float)va[ii].y * c);   // (sr',-si')
            }
        }
        __syncthreads();                       // (2) S' ready; P (old W^T) dead

        // ---- PHASE B (MFMA): G[n][l]; af = paf regs; G planes -> P.
        // bf rows lr>=40: clamp only (garbage -> l>=40 outputs, skipped).
        f32x4 gRe[3], gIm[3];
        #pragma unroll
        for (int ct = 0; ct < 3; ++ct) { gRe[ct] = (f32x4){0.f,0.f,0.f,0.f}; gIm[ct] = (f32x4){0.f,0.f,0.f,0.f}; }
        {
            #pragma unroll
            for (int q = 0; q < 3; ++q) {
                h16x8 af = paf[q];
                #pragma unroll
                for (int ct = 0; ct < 3; ++ct) {
                    int lr = col + 16*ct;
                    int lrC = (lr < KK) ? lr : 0;
                    h16x8 bf = *(const h16x8*)(sh + Q + lrC*128 + SWZ(lrC, g*8 + 32*q));
                    gRe[ct] = MFMA16(af, bf, gRe[ct]);
                    gIm[ct] = MFMA16(af, imB(bf), gIm[ct]);
                }
            }
        }
        {
            const int n0w = 16*wv + 4*g;
            #pragma unroll
            for (int ct = 0; ct < 3; ++ct) {
                int l = col + 16*ct;
                if (l < KK) {
                    h16x4 g4, q4;
                    #pragma unroll
                    for (int r = 0; r < 4; ++r) {
                        g4[r] = (h16)(gRe[ct][r] - cpen * Wr[ct][r]);
                        q4[r] = (h16)(gIm[ct][r] - cpen * Wi[ct][r]);
                    }
                    *(h16x4*)(sh + GREo + l*64 + SWZ(l, n0w)) = g4;
                    *(h16x4*)(sh + GIMo + l*64 + SWZ(l, n0w)) = q4;
                }
            }
        }
        __syncthreads();                       // (3) G planes visible; Q dead

        // ---- PHASE C (MFMA): Ug = U x G. fre/fim rows l>=40: clamp only.
        f32x4 cRe[3], cIm[3];
        #pragma unroll
        for (int ct = 0; ct < 3; ++ct) { cRe[ct] = (f32x4){0.f,0.f,0.f,0.f}; cIm[ct] = (f32x4){0.f,0.f,0.f,0.f}; }
        {
            const int nrow = col + 16*wv;
            #pragma unroll
            for (int q = 0; q < 2; ++q) {
                h16x8 af = *(const h16x8*)(sh + UOF + nrow*64 + SWZ(nrow, g*8 + 32*q));
                #pragma unroll
                for (int ct = 0; ct < 3; ++ct) {
                    const int l = col + 16*ct;
                    const int lC = (l < KK) ? l : 0;
                    h16x8 fre = *(const h16x8*)(sh + GREo + lC*64 + SWZ(lC, g*8 + 32*q));
                    h16x8 fim = *(const h16x8*)(sh + GIMo + lC*64 + SWZ(lC, g*8 + 32*q));
                    cRe[ct] = MFMA16(af, fre, cRe[ct]);
                    cIm[ct] = MFMA16(af, fim, cIm[ct]);
                }
            }
        }
        float ps2 = 0.f;
        {
            const int n0w = 16*wv + 4*g;
            #pragma unroll
            for (int ct = 0; ct < 3; ++ct) {
                int l = col + 16*ct;
                h16x8 wvv;
                #pragma unroll
                for (int r = 0; r < 4; ++r) {
                    float ur = cRe[ct][r], ui = cIm[ct][r];
                    float wr = Wr[ct][r] - etat*(ur - ui) + breg[ct][r];
                    float wi = Wi[ct][r] - etat*(ui + ur);
                    Wr[ct][r] = wr; Wi[ct][r] = wi;
                    wvv[2*r]   = (h16)wr;
                    wvv[2*r+1] = (h16)wi;
                    if (l < KK) ps2 += wr*wr + wi*wi;
                }
                if (t < NL-1 && l < KK)
                    *(h16x8*)(sh + Q + l*128 + SWZW(l, 2*n0w)) = wvv;
            }
        }
        #pragma unroll
        for (int off = 32; off; off >>= 1) ps2 += __shfl_down(ps2, off, 64);
        if (ln == 0) sRed[wv] = ps2;
        __syncthreads();                       // (4) layer end
    }

    // ---- final normalization from registers
    const float pwf   = sRed[0] + sRed[1] + sRed[2] + sRed[3];
    const float scale = 1.0f / (sqrtf(pwf) + 1e-6f);

    if (outFloats >= 2 * NBATCH * NT * KK) {
        float2* ob = (float2*)(gOut + (size_t)bb * NT * KK * 2);
        #pragma unroll
        for (int ct = 0; ct < 3; ++ct)
            #pragma unroll
            for (int r = 0; r < 4; ++r) {
                int n = 16*wv + 4*g + r, l = col + 16*ct;
                if (l < KK) {
                    float2 v; v.x = Wr[ct][r]*scale; v.y = Wi[ct][r]*scale;
                    ob[n*KK + l] = v;
                }
            }
    } else {
        float* ob = gOut + (size_t)bb * NT * KK;
        #pragma unroll
        for (int ct = 0; ct < 3; ++ct)
            #pragma unroll
            for (int r = 0; r < 4; ++r) {
                int n = 16*wv + 4*g + r, l = col + 16*ct;
                if (l < KK) ob[n*KK + l] = Wr[ct][r] * scale;
            }
    }
}

extern "C" void kernel_launch(void* const* d_in, const int* in_sizes, int n_in,
                              void* d_out, int out_size, void* d_ws, size_t ws_size,
                              hipStream_t stream) {
    (void)in_sizes; (void)n_in; (void)d_ws; (void)ws_size;
    const float* Hr  = (const float*)d_in[0];
    const float* Hi  = (const float*)d_in[1];
    const float* eta = (const float*)d_in[2];
    const float* U   = (const float*)d_in[3];
    const float* b   = (const float*)d_in[4];
    float* out = (float*)d_out;
    gpnet_kernel<<<NBATCH, 256, 0, stream>>>(Hr, Hi, eta, U, b, out, out_size);
}